// Round 17
// baseline (341.149 us; speedup 1.0000x reference)
//
#include <hip/hip_runtime.h>

// ComplexAttention: B=4, S=2048, D=1024 -> single-head attention, head_dim 2048.
// R17: 256x128 tile, TRIPLE-buffered LDS (3x48KB=144KB), full next-tile read-ahead.
// acc shrinks 128->64 regs (per-wave 128x32) -> next-tile frag set (20 b128) fits
// in registers (R3/R7/R13 spilled only because 256x256's acc=128 left no room).
// Per segment: {read tile t+1 <- nxt; stage t+2 -> stg; MM(tile t from regs);
// vmcnt(0); barrier; rotate bufs}.  MM starts instantly post-barrier (operands
// pre-read) -> segment-boundary latency (the measured ~2400cyc/K-tile gap vs the
// 2484cyc MFMA floor) hides under compute.  Frag sets alternate by 2-unroll
// (named X/Y, rule-20-safe); LDS bufs rotate via register pointers.
// RAW: nxt staged seg t-1, own-vmcnt(0)+BAR before reads.  WAR: stg's last reads
// were lgkm-consumed by MM one barrier earlier.  + bijective XCD chunk swizzle.

typedef short  bf16x8 __attribute__((ext_vector_type(8)));
typedef _Float16 f16x8 __attribute__((ext_vector_type(8)));
typedef float  f32x4  __attribute__((ext_vector_type(4)));
typedef unsigned short u16;

typedef __attribute__((address_space(3))) void       lds_void;
typedef const __attribute__((address_space(1))) void g_void;

__device__ __forceinline__ u16 f2bf(float f) {
  union { float f; unsigned u; } v; v.f = f;
  unsigned r = v.u + 0x7FFFu + ((v.u >> 16) & 1u);   // round-to-nearest-even
  return (u16)(r >> 16);
}
__device__ __forceinline__ u16 f2h(float f) {
  union { _Float16 h; u16 u; } v; v.h = (_Float16)f;
  return v.u;
}
__device__ __forceinline__ float h2f(u16 u) {
  union { u16 u; _Float16 h; } v; v.u = u;
  return (float)v.h;
}

// ---------------- fp32 -> bf16 convert (vectorized) ----------------
__global__ __launch_bounds__(256) void cvt_f32_bf16(const float* __restrict__ in,
                                                    u16* __restrict__ out, int n4) {
  int i = blockIdx.x * 256 + threadIdx.x;
  if (i >= n4) return;
  const float4 v = ((const float4*)in)[i];
  union { u16 us[4]; unsigned long long ll; } u;
  u.us[0] = f2bf(v.x); u.us[1] = f2bf(v.y); u.us[2] = f2bf(v.z); u.us[3] = f2bf(v.w);
  ((unsigned long long*)out)[i] = u.ll;
}

// ---------- 256x128 NT GEMM, triple-buffer LDS, read-ahead, 1 barrier/K-tile ----
// C[m,n] = alpha*sum_k A[m,k]*B[n,k] (+bias[n]).  A,B 16-bit row-major (K contig).
// CMODE: 0=fp32 C, 1=bf16 C, 2=fp16 transposed-V Vt[b][n][t], 3=fp16 C.
// FT: 0=bf16 MFMA, 1=fp16 MFMA.  512 thr = 8 waves (2M x 4N), per-wave 128x32.
// LDS buf i @ i*24576 u16: A [256][64] @0 (16384), B [128][64] @16384 (8192).
// Stage: 6 glds/thread-tile (A q=0..3, B q=0..1), chunk row=q*64+(tid>>3),
// pre-swizzled src chunk ((tid&7)^((tid>>3)&7)); dest = buf + regionoff + q*4096
// + tid*8.  Reads: row*64 + ((kk*4+ko)^(fr&7))*8 (row&7==fr&7 invariant).
template<int CMODE, bool BIAS, int FT>
__global__ __launch_bounds__(512, 2) void gemmK(const u16* __restrict__ A,
                                                const u16* __restrict__ B,
                                                void* __restrict__ Cv,
                                                const float* __restrict__ bias,
                                                int K, int lda, int ldb, int ldc,
                                                long bsA, long bsB, long bsC,
                                                float alpha)
{
  __shared__ u16 sm[73728];                  // 3 x (16384 A + 8192 B) u16 = 144 KB
  // bijective XCD chunk swizzle (all grids divisible by 8)
  const int gx = gridDim.x, gy = gridDim.y;
  const int nb = gx * gy * gridDim.z;
  const int bid0 = blockIdx.x + gx * (blockIdx.y + gy * blockIdx.z);
  const int nsw = (bid0 & 7) * (nb >> 3) + (bid0 >> 3);
  const int bx = nsw % gx, by = (nsw / gx) % gy, bz = nsw / (gx * gy);

  const u16* Ab = A + (long)bz * bsA;
  const u16* Bb = B + (long)bz * bsB;
  const int m0 = by * 256, n0 = bx * 128;
  const int tid = threadIdx.x, lane = tid & 63, w = tid >> 6;
  const int wmr = w >> 2, wnr = w & 3;
  const int fr = lane & 15, ko = lane >> 4;

  f32x4 acc[8][2] = {};
  bf16x8 afX[16], afY[16], bfX[4], bfY[4];

  // per-lane read offsets (u16 units, relative to buf base)
  const int swz0 = ((0 + ko) ^ (fr & 7)) * 8;
  const int swz1 = ((4 + ko) ^ (fr & 7)) * 8;
  const int aoff0 = (wmr * 128 + fr) * 64 + swz0;
  const int aoff1 = (wmr * 128 + fr) * 64 + swz1;
  const int boff0 = 16384 + (wnr * 32 + fr) * 64 + swz0;
  const int boff1 = 16384 + (wnr * 32 + fr) * 64 + swz1;

#define LDAm(dst, base)                                                         \
  { _Pragma("unroll") for (int mi = 0; mi < 8; ++mi) {                          \
      dst[mi * 2 + 0] = *(const bf16x8*)((base) + aoff0 + mi * 1024);           \
      dst[mi * 2 + 1] = *(const bf16x8*)((base) + aoff1 + mi * 1024); } }
#define LDBm(dst, base)                                                         \
  { _Pragma("unroll") for (int ni = 0; ni < 2; ++ni) {                          \
      dst[ni * 2 + 0] = *(const bf16x8*)((base) + boff0 + ni * 1024);           \
      dst[ni * 2 + 1] = *(const bf16x8*)((base) + boff1 + ni * 1024); } }

  // staging pointers (advance +64 elems per staged K-tile)
  const int trow = tid >> 3;
  const int c8 = ((tid & 7) ^ (trow & 7)) * 8;
  const u16* pA0 = Ab + (long)(m0 + trow) * lda + c8;
  const u16* pA1 = Ab + (long)(m0 + 64 + trow) * lda + c8;
  const u16* pA2 = Ab + (long)(m0 + 128 + trow) * lda + c8;
  const u16* pA3 = Ab + (long)(m0 + 192 + trow) * lda + c8;
  const u16* pB0 = Bb + (long)(n0 + trow) * ldb + c8;
  const u16* pB1 = Bb + (long)(n0 + 64 + trow) * ldb + c8;

#define GL(p, d) __builtin_amdgcn_global_load_lds((g_void*)(p), (lds_void*)(d), 16, 0, 0);
#define STG(base)                                                               \
  { GL(pA0, (base) + 0     + tid * 8) GL(pA1, (base) + 4096  + tid * 8)         \
    GL(pA2, (base) + 8192  + tid * 8) GL(pA3, (base) + 12288 + tid * 8)         \
    GL(pB0, (base) + 16384 + tid * 8) GL(pB1, (base) + 20480 + tid * 8)         \
    pA0 += 64; pA1 += 64; pA2 += 64; pA3 += 64; pB0 += 64; pB1 += 64; }

  auto MM = [&](const bf16x8* af, const bf16x8* bf) {
    __builtin_amdgcn_s_setprio(1);
#pragma unroll
    for (int mi = 0; mi < 8; ++mi)
#pragma unroll
      for (int ni = 0; ni < 2; ++ni)
#pragma unroll
        for (int kk = 0; kk < 2; ++kk) {
          if constexpr (FT == 0)
            acc[mi][ni] = __builtin_amdgcn_mfma_f32_16x16x32_bf16(
                af[mi * 2 + kk], bf[ni * 2 + kk], acc[mi][ni], 0, 0, 0);
          else
            acc[mi][ni] = __builtin_amdgcn_mfma_f32_16x16x32_f16(
                __builtin_bit_cast(f16x8, af[mi * 2 + kk]),
                __builtin_bit_cast(f16x8, bf[ni * 2 + kk]),
                acc[mi][ni], 0, 0, 0);
        }
    __builtin_amdgcn_s_setprio(0);
  };

// segment t: read tile t+1 into set N from nxt; stage tile t+2 -> stg;
// MM tile t from set C (pre-read); drain own stages; barrier; rotate bufs.
#define SEG(AFC, BFC, AFN, BFN, t)                                              \
  { if ((t) + 1 < nt) { LDAm(AFN, nxt) LDBm(BFN, nxt) }                         \
    if ((t) + 2 < nt) { STG(stg) }                                              \
    MM(AFC, BFC);                                                               \
    asm volatile("s_waitcnt vmcnt(0)" ::: "memory");                            \
    asm volatile("s_barrier" ::: "memory");                                     \
    u16* rt_ = cur; cur = nxt; nxt = stg; stg = rt_; }

  const int nt = K >> 6;
  u16 *cur = sm, *nxt = sm + 24576, *stg = sm + 49152;

  // prologue: tiles 0,1 -> buf0,buf1; drain; barrier; pre-read tile 0 -> set X.
  STG(cur)
  STG(nxt)
  asm volatile("s_waitcnt vmcnt(0)" ::: "memory");
  asm volatile("s_barrier" ::: "memory");
  LDAm(afX, cur) LDBm(bfX, cur)

  for (int t = 0; t < nt; t += 2) {
    SEG(afX, bfX, afY, bfY, t)
    SEG(afY, bfY, afX, bfX, t + 1)
  }

  // epilogue: C/D frag layout col=lane&15, row=(lane>>4)*4+r  (m89-verified)
  const int col = lane & 15, rb = (lane >> 4) * 4;
#pragma unroll
  for (int mi = 0; mi < 8; ++mi) {
#pragma unroll
    for (int ni = 0; ni < 2; ++ni) {
      const int mg = m0 + wmr * 128 + mi * 16 + rb;
      const int ng = n0 + wnr * 32 + ni * 16 + col;
      const float bvv = BIAS ? bias[ng] : 0.0f;
      if constexpr (CMODE == 2) {
        u16* Cc = (u16*)Cv;
        const long bb = mg >> 11;
        const int  t  = mg & 2047;
        union { u16 us[4]; unsigned long long ll; } u;
#pragma unroll
        for (int r = 0; r < 4; ++r) u.us[r] = f2h(acc[mi][ni][r] * alpha + bvv);
        *(unsigned long long*)(Cc + bb * 4194304 + (long)ng * 2048 + t) = u.ll;
      } else if constexpr (CMODE == 1 || CMODE == 3) {
        u16* Cc = (u16*)Cv + (long)bz * bsC;
#pragma unroll
        for (int r = 0; r < 4; ++r) {
          const float x = acc[mi][ni][r] * alpha + bvv;
          Cc[(long)(mg + r) * ldc + ng] = (CMODE == 1) ? f2bf(x) : f2h(x);
        }
      } else {
        float* Cf = (float*)Cv + (long)bz * bsC;
#pragma unroll
        for (int r = 0; r < 4; ++r)
          Cf[(long)(mg + r) * ldc + ng] = acc[mi][ni][r] * alpha + bvv;
      }
    }
  }
#undef LDAm
#undef LDBm
#undef GL
#undef STG
#undef SEG
}

// ---------------- row softmax: fp16 scores row (2048) -> fp16 P ----------------
__global__ __launch_bounds__(256) void softmax_f16(const u16* __restrict__ Scb,
                                                   u16* __restrict__ Pb) {
  const int tid = threadIdx.x;
  const long row = blockIdx.x;
  union { int4 v; u16 us[8]; } u;
  u.v = ((const int4*)(Scb + row * 2048))[tid];
  float f[8];
#pragma unroll
  for (int j = 0; j < 8; ++j) f[j] = h2f(u.us[j]);
  float mx = f[0];
#pragma unroll
  for (int j = 1; j < 8; ++j) mx = fmaxf(mx, f[j]);
  __shared__ float red[8];
  const int lane = tid & 63, wid = tid >> 6;
#pragma unroll
  for (int off = 32; off; off >>= 1) mx = fmaxf(mx, __shfl_down(mx, off));
  if (!lane) red[wid] = mx;
  __syncthreads();
  mx = fmaxf(fmaxf(red[0], red[1]), fmaxf(red[2], red[3]));
  float e[8], s = 0.f;
#pragma unroll
  for (int j = 0; j < 8; ++j) { e[j] = __expf(f[j] - mx); s += e[j]; }
#pragma unroll
  for (int off = 32; off; off >>= 1) s += __shfl_down(s, off);
  if (!lane) red[4 + wid] = s;
  __syncthreads();
  s = red[4] + red[5] + red[6] + red[7];
  const float inv = 1.0f / s;
  union { u16 us[8]; int4 v; } o;
#pragma unroll
  for (int j = 0; j < 8; ++j) o.us[j] = f2h(e[j] * inv);
  ((int4*)(Pb + row * 2048))[tid] = o.v;
}

extern "C" void kernel_launch(void* const* d_in, const int* in_sizes, int n_in,
                              void* d_out, int out_size, void* d_ws, size_t ws_size,
                              hipStream_t stream) {
  const float* X  = (const float*)d_in[0];
  const float* Wq = (const float*)d_in[1];
  const float* bq = (const float*)d_in[2];
  const float* Wk = (const float*)d_in[3];
  const float* bk = (const float*)d_in[4];
  const float* Wv = (const float*)d_in[5];
  const float* bv = (const float*)d_in[6];
  const float* Wo = (const float*)d_in[7];
  const float* bo = (const float*)d_in[8];
  float* out = (float*)d_out;

  char* w = (char*)d_ws;
  u16* Xb  = (u16*)w; w += (size_t)8192 * 1024 * 2;
  u16* Wqb = (u16*)w; w += (size_t)2048 * 1024 * 2;
  u16* Wkb = (u16*)w; w += (size_t)2048 * 1024 * 2;
  u16* Wvb = (u16*)w; w += (size_t)2048 * 1024 * 2;
  u16* Wob = (u16*)w; w += (size_t)1024 * 2048 * 2;
  u16* Qb  = (u16*)w; w += (size_t)8192 * 2048 * 2;
  u16* Kb  = (u16*)w; w += (size_t)8192 * 2048 * 2;
  u16* Vt  = (u16*)w; w += (size_t)8192 * 2048 * 2;   // fp16 [4][2048 d][2048 t]
  u16* AO  = (u16*)w; w += (size_t)8192 * 2048 * 2;
  u16* Scb = (u16*)w; w += (size_t)8192 * 2048 * 2;   // fp16 scores
  u16* Pb  = (u16*)w; w += (size_t)8192 * 2048 * 2;   // fp16 P
  if ((size_t)(w - (char*)d_ws) > ws_size) return;

  cvt_f32_bf16<<<8192, 256, 0, stream>>>(X,  Xb,  8192 * 1024 / 4);
  cvt_f32_bf16<<<2048, 256, 0, stream>>>(Wq, Wqb, 2048 * 1024 / 4);
  cvt_f32_bf16<<<2048, 256, 0, stream>>>(Wk, Wkb, 2048 * 1024 / 4);
  cvt_f32_bf16<<<2048, 256, 0, stream>>>(Wv, Wvb, 2048 * 1024 / 4);
  cvt_f32_bf16<<<2048, 256, 0, stream>>>(Wo, Wob, 1024 * 2048 / 4);

  // projections: M=8192, N=2048, K=1024 (grid 512 blocks)
  gemmK<1, true, 0><<<dim3(16, 32, 1), 512, 0, stream>>>(Xb, Wqb, Qb, bq,
      1024, 1024, 1024, 2048, 0, 0, 0, 1.0f);
  gemmK<1, true, 0><<<dim3(16, 32, 1), 512, 0, stream>>>(Xb, Wkb, Kb, bk,
      1024, 1024, 1024, 2048, 0, 0, 0, 1.0f);
  gemmK<2, true, 0><<<dim3(16, 32, 1), 512, 0, stream>>>(Xb, Wvb, Vt, bv,
      1024, 1024, 1024, 0, 0, 0, 0, 1.0f);

  // scores: per-batch 2048x2048, K=2048 -> fp16 Sc  (grid 512)
  gemmK<3, false, 0><<<dim3(16, 8, 4), 512, 0, stream>>>(Qb, Kb, Scb, nullptr,
      2048, 2048, 2048, 2048, 4194304, 4194304, 4194304, 0.03125f);

  softmax_f16<<<8192, 256, 0, stream>>>(Scb, Pb);

  // O = P @ Vt^T : fp16 MFMA -> bf16 AO  (grid 512)
  gemmK<1, false, 1><<<dim3(16, 8, 4), 512, 0, stream>>>(Pb, Vt, AO, nullptr,
      2048, 2048, 2048, 2048, 4194304, 4194304, 4194304, 1.0f);

  // out = AO @ Wo^T + bo : M=8192, N=1024, K=2048, fp32 out (grid 256)
  gemmK<0, true, 0><<<dim3(8, 32, 1), 512, 0, stream>>>(AO, Wob, out, bo,
      2048, 2048, 2048, 1024, 0, 0, 0, 1.0f);
}

// Round 18
// 307.416 us; speedup vs baseline: 1.1097x; 1.1097x over previous
//
#include <hip/hip_runtime.h>

// ComplexAttention: B=4, S=2048, D=1024 -> single-head attention, head_dim 2048:
// Q/K/V = X@W^T+b ; S = Q@K^T/32 ; P = softmax(S) ; O = P@V ; out = O@Wo^T + bo.
// R18 = R16 (best measured: 314.9us) with the 5 convert launches merged into 1.
// GEMM: R15/R16 proven kernel -- 256x(NH*128) tile, 1 barrier/K-tile, same-phase
// reads, hoisted swizzled addressing, fp16 softmax path (Sc/P/V fp16, PV mfma-f16).
// Schedule axis exhausted: 37-46% MfmaUtil over 7 structural variants; cross-phase
// read-ahead spills (acc=128 AGPRs cap arch VGPRs: R3/R7/R13); 256x128 + 3-buf
// regressed (R17: worse MFMA:LDS ratio).  This is the plateau configuration.

typedef short  bf16x8 __attribute__((ext_vector_type(8)));
typedef _Float16 f16x8 __attribute__((ext_vector_type(8)));
typedef float  f32x4  __attribute__((ext_vector_type(4)));
typedef unsigned short u16;

typedef __attribute__((address_space(3))) void       lds_void;
typedef const __attribute__((address_space(1))) void g_void;

__device__ __forceinline__ u16 f2bf(float f) {
  union { float f; unsigned u; } v; v.f = f;
  unsigned r = v.u + 0x7FFFu + ((v.u >> 16) & 1u);   // round-to-nearest-even
  return (u16)(r >> 16);
}
__device__ __forceinline__ u16 f2h(float f) {
  union { _Float16 h; u16 u; } v; v.h = (_Float16)f;
  return v.u;
}
__device__ __forceinline__ float h2f(u16 u) {
  union { u16 u; _Float16 h; } v; v.u = u;
  return (float)v.h;
}

// ------------- fp32 -> bf16 convert, ALL tensors in one launch -------------
// blocks 0..8191: X (2097152 f4); then 4 x 2048 blocks: Wq, Wk, Wv, Wo
// (524288 f4 each).  All counts are exact multiples of 256 -> no bounds checks.
__global__ __launch_bounds__(256) void cvt_all(
    const float* __restrict__ X,  const float* __restrict__ Wq,
    const float* __restrict__ Wk, const float* __restrict__ Wv,
    const float* __restrict__ Wo, u16* __restrict__ Xb, u16* __restrict__ Wqb,
    u16* __restrict__ Wkb, u16* __restrict__ Wvb, u16* __restrict__ Wob) {
  const int bid = blockIdx.x;
  const float* in; u16* out; int lb;
  if (bid < 8192) { in = X; out = Xb; lb = bid; }
  else {
    const int r = bid - 8192, s = r >> 11; lb = r & 2047;
    in  = (s == 0) ? Wq  : (s == 1) ? Wk  : (s == 2) ? Wv  : Wo;
    out = (s == 0) ? Wqb : (s == 1) ? Wkb : (s == 2) ? Wvb : Wob;
  }
  const int i = lb * 256 + threadIdx.x;
  const float4 v = ((const float4*)in)[i];
  union { u16 us[4]; unsigned long long ll; } u;
  u.us[0] = f2bf(v.x); u.us[1] = f2bf(v.y); u.us[2] = f2bf(v.z); u.us[3] = f2bf(v.w);
  ((unsigned long long*)out)[i] = u.ll;
}

// ---------------- 256x(NH*128) NT GEMM, 1 barrier/K-tile, hoisted addressing ----
// C[m,n] = alpha * sum_k A[m,k]*B[n,k] (+ bias[n]).  A,B 16-bit row-major (K contig).
// CMODE: 0=fp32 C, 1=bf16 C, 2=fp16 transposed-V write Vt[b][n][t], 3=fp16 C.
// FT: 0 = bf16 MFMA inputs, 1 = fp16 MFMA inputs (same frag & C/D layout).
// 512 thr = 8 waves (2M x 4N); BK=64; LDS: A [2][256][64]u16 @0, B [2][..][64] @32768.
// LDS u16 layout per (operand,dbuf): half*8192 + q*4096 + w*512 + lane*8 (16B/lane);
// swizzle slot (c^(r&7)) loop-invariant per lane.  Safety (R11/R15, ref-passed):
// per K-tile segment {reads+MMs; stage other buf; own vmcnt(0); BAR}.
template<int CMODE, bool BIAS, int NH, int FT>
__global__ __launch_bounds__(512, 2) void gemmK(const u16* __restrict__ A,
                                                const u16* __restrict__ B,
                                                void* __restrict__ Cv,
                                                const float* __restrict__ bias,
                                                int K, int lda, int ldb, int ldc,
                                                long bsA, long bsB, long bsC,
                                                float alpha)
{
  __shared__ u16 sm[65536];
  const int bz = blockIdx.z;
  const u16* Ab = A + (long)bz * bsA;
  const u16* Bb = B + (long)bz * bsB;
  const int m0 = blockIdx.y * 256, n0 = blockIdx.x * (NH * 128);
  const int tid = threadIdx.x, lane = tid & 63, w = tid >> 6;
  const int wmr = w >> 2, wnr = w & 3;
  const int fr = lane & 15, ko = lane >> 4;

  f32x4 acc[8][2 * NH] = {};
  bf16x8 afA[8], afB[8], bfA[4], bfB[4];

  // ---- hoisted LDS read bases (u16 units; loop-invariant per lane) ----
  const u16* aP0 = sm + wmr * 8192 + fr * 64 + (((0 + ko) ^ (fr & 7)) * 8);  // kk=0
  const u16* aP1 = sm + wmr * 8192 + fr * 64 + (((4 + ko) ^ (fr & 7)) * 8);  // kk=1
  const u16* bP0 = sm + 32768 + wnr * (NH * 32) * 64 + fr * 64 + (((0 + ko) ^ (fr & 7)) * 8);
  const u16* bP1 = sm + 32768 + wnr * (NH * 32) * 64 + fr * 64 + (((4 + ko) ^ (fr & 7)) * 8);

// frag reads: all offsets compile-time (D,MH,NHh literals; mi,ni unrolled)
#define LDAf(dst, D, MH)                                                        \
  { _Pragma("unroll") for (int mi = 0; mi < 4; ++mi) {                          \
      dst[mi * 2 + 0] = *(const bf16x8*)(aP0 + (D) * 16384 + (MH) * 4096 + mi * 1024); \
      dst[mi * 2 + 1] = *(const bf16x8*)(aP1 + (D) * 16384 + (MH) * 4096 + mi * 1024); } }
#define LDBf(dst, D, NHh)                                                       \
  { _Pragma("unroll") for (int ni = 0; ni < 2; ++ni) {                          \
      dst[ni * 2 + 0] = *(const bf16x8*)(bP0 + (D) * 16384 + (NHh) * 2048 + ni * 1024); \
      dst[ni * 2 + 1] = *(const bf16x8*)(bP1 + (D) * 16384 + (NHh) * 2048 + ni * 1024); } }

  // ---- hoisted staging pointers: lane's 16B chunk, row rl = q*64 + w*8 + (lane>>3),
  //      pre-swizzled src col c = ((lane&7) ^ (lane>>3)) * 8  (q/half-invariant) ----
  const int lrow = w * 8 + (lane >> 3);
  const int c8 = ((lane & 7) ^ (lane >> 3)) * 8;
  const long dA = (long)lda * 64, dB = (long)ldb * 64;
  const u16* pA00 = Ab + (long)(m0 + lrow) * lda + c8;       // half0,q0
  const u16* pA01 = pA00 + dA;                               // half0,q1 (+64 rows)
  const u16* pA10 = pA00 + 2 * dA;                           // half1,q0
  const u16* pA11 = pA00 + 3 * dA;                           // half1,q1
  const u16* pB00 = Bb + (long)(n0 + lrow) * ldb + c8;
  const u16* pB01 = pB00 + dB;
  const u16* pB10 = pB00 + 2 * dB;                           // NH==2 only
  const u16* pB11 = pB00 + 3 * dB;
  u16* dstB = sm + w * 512;                                  // + const per call

#define STG(ptr, CONSTOFF)                                                      \
  __builtin_amdgcn_global_load_lds((g_void*)(ptr), (lds_void*)(dstB + (CONSTOFF)), 16, 0, 0);
  // dest const (u16): (isA?0:32768) + D*16384 + HALF*8192 + Q*4096
#define STG_A(D) { STG(pA00, (D)*16384 + 0)        STG(pA01, (D)*16384 + 4096)  \
                   STG(pA10, (D)*16384 + 8192)     STG(pA11, (D)*16384 + 12288) \
                   pA00 += 64; pA01 += 64; pA10 += 64; pA11 += 64; }
#define STG_B2(D) { STG(pB00, 32768 + (D)*16384 + 0)    STG(pB01, 32768 + (D)*16384 + 4096)  \
                    STG(pB10, 32768 + (D)*16384 + 8192) STG(pB11, 32768 + (D)*16384 + 12288) \
                    pB00 += 64; pB01 += 64; pB10 += 64; pB11 += 64; }
#define STG_B1(D) { STG(pB00, 32768 + (D)*16384 + 0)    STG(pB01, 32768 + (D)*16384 + 4096)  \
                    pB00 += 64; pB01 += 64; }

  auto MM = [&](const bf16x8* af, const bf16x8* bf, int mb, int nb) {
    __builtin_amdgcn_s_setprio(1);
#pragma unroll
    for (int mi = 0; mi < 4; ++mi)
#pragma unroll
      for (int ni = 0; ni < 2; ++ni)
#pragma unroll
        for (int kk = 0; kk < 2; ++kk) {
          if constexpr (FT == 0)
            acc[mb + mi][nb + ni] = __builtin_amdgcn_mfma_f32_16x16x32_bf16(
                af[mi * 2 + kk], bf[ni * 2 + kk], acc[mb + mi][nb + ni], 0, 0, 0);
          else
            acc[mb + mi][nb + ni] = __builtin_amdgcn_mfma_f32_16x16x32_f16(
                __builtin_bit_cast(f16x8, af[mi * 2 + kk]),
                __builtin_bit_cast(f16x8, bf[ni * 2 + kk]),
                acc[mb + mi][nb + ni], 0, 0, 0);
        }
    __builtin_amdgcn_s_setprio(0);
  };

// one K-tile on buffer D; stages next tile into buffer D^1 when SEN
#define KTILE2(D, SEN)                                                          \
  { LDAf(afA, D, 0) LDBf(bfA, D, 0)                                             \
    if (SEN) { STG_A(D ^ 1) }                                                   \
    MM(afA, bfA, 0, 0);                                                         \
    LDBf(bfB, D, 1)                                                             \
    if (SEN) { STG_B2(D ^ 1) }                                                  \
    MM(afA, bfB, 0, 2);                                                         \
    LDAf(afB, D, 1)                                                             \
    MM(afB, bfB, 4, 2);                                                         \
    MM(afB, bfA, 4, 0);                                                         \
    asm volatile("s_waitcnt vmcnt(0)" ::: "memory");                            \
    asm volatile("s_barrier" ::: "memory"); }
#define KTILE1(D, SEN)                                                          \
  { LDAf(afA, D, 0) LDBf(bfA, D, 0)                                             \
    if (SEN) { STG_A(D ^ 1) }                                                   \
    MM(afA, bfA, 0, 0);                                                         \
    LDAf(afB, D, 1)                                                             \
    if (SEN) { STG_B1(D ^ 1) }                                                  \
    MM(afB, bfA, 4, 0);                                                         \
    asm volatile("s_waitcnt vmcnt(0)" ::: "memory");                            \
    asm volatile("s_barrier" ::: "memory"); }

  const int nt = K >> 6, niter = nt >> 1;

  // prologue: tile 0 -> buf0; own-drain; barrier.
  STG_A(0)
  if constexpr (NH == 2) { STG_B2(0) } else { STG_B1(0) }
  asm volatile("s_waitcnt vmcnt(0)" ::: "memory");
  asm volatile("s_barrier" ::: "memory");

  for (int j = 0; j < niter; ++j) {
    const bool pre = (j + 1 < niter);
    if constexpr (NH == 2) {
      KTILE2(0, true)          // tile 2j   (buf0), stages 2j+1 -> buf1
      KTILE2(1, pre)           // tile 2j+1 (buf1), stages 2j+2 -> buf0
    } else {
      KTILE1(0, true)
      KTILE1(1, pre)
    }
  }

  // epilogue: C/D frag layout col=lane&15, row=(lane>>4)*4+r  (m89-verified)
  const int col = lane & 15, rb = (lane >> 4) * 4;
#pragma unroll
  for (int mi = 0; mi < 8; ++mi) {
#pragma unroll
    for (int ni = 0; ni < 2 * NH; ++ni) {
      const int mg = m0 + wmr * 128 + mi * 16 + rb;
      const int ng = n0 + wnr * (NH * 32) + ni * 16 + col;
      const float bvv = BIAS ? bias[ng] : 0.0f;
      if constexpr (CMODE == 2) {
        u16* Cc = (u16*)Cv;
        const long bb = mg >> 11;
        const int  t  = mg & 2047;
        union { u16 us[4]; unsigned long long ll; } u;
#pragma unroll
        for (int r = 0; r < 4; ++r) u.us[r] = f2h(acc[mi][ni][r] * alpha + bvv);
        *(unsigned long long*)(Cc + bb * 4194304 + (long)ng * 2048 + t) = u.ll;
      } else if constexpr (CMODE == 1 || CMODE == 3) {
        u16* Cc = (u16*)Cv + (long)bz * bsC;
#pragma unroll
        for (int r = 0; r < 4; ++r) {
          const float x = acc[mi][ni][r] * alpha + bvv;
          Cc[(long)(mg + r) * ldc + ng] = (CMODE == 1) ? f2bf(x) : f2h(x);
        }
      } else {
        float* Cf = (float*)Cv + (long)bz * bsC;
#pragma unroll
        for (int r = 0; r < 4; ++r)
          Cf[(long)(mg + r) * ldc + ng] = acc[mi][ni][r] * alpha + bvv;
      }
    }
  }
#undef LDAf
#undef LDBf
#undef STG
#undef STG_A
#undef STG_B2
#undef STG_B1
#undef KTILE2
#undef KTILE1
}

// ---------------- row softmax: fp16 scores row (2048) -> fp16 P ----------------
__global__ __launch_bounds__(256) void softmax_f16(const u16* __restrict__ Scb,
                                                   u16* __restrict__ Pb) {
  const int tid = threadIdx.x;
  const long row = blockIdx.x;
  union { int4 v; u16 us[8]; } u;
  u.v = ((const int4*)(Scb + row * 2048))[tid];
  float f[8];
#pragma unroll
  for (int j = 0; j < 8; ++j) f[j] = h2f(u.us[j]);
  float mx = f[0];
#pragma unroll
  for (int j = 1; j < 8; ++j) mx = fmaxf(mx, f[j]);
  __shared__ float red[8];
  const int lane = tid & 63, wid = tid >> 6;
#pragma unroll
  for (int off = 32; off; off >>= 1) mx = fmaxf(mx, __shfl_down(mx, off));
  if (!lane) red[wid] = mx;
  __syncthreads();
  mx = fmaxf(fmaxf(red[0], red[1]), fmaxf(red[2], red[3]));
  float e[8], s = 0.f;
#pragma unroll
  for (int j = 0; j < 8; ++j) { e[j] = __expf(f[j] - mx); s += e[j]; }
#pragma unroll
  for (int off = 32; off; off >>= 1) s += __shfl_down(s, off);
  if (!lane) red[4 + wid] = s;
  __syncthreads();
  s = red[4] + red[5] + red[6] + red[7];
  const float inv = 1.0f / s;
  union { u16 us[8]; int4 v; } o;
#pragma unroll
  for (int j = 0; j < 8; ++j) o.us[j] = f2h(e[j] * inv);
  ((int4*)(Pb + row * 2048))[tid] = o.v;
}

extern "C" void kernel_launch(void* const* d_in, const int* in_sizes, int n_in,
                              void* d_out, int out_size, void* d_ws, size_t ws_size,
                              hipStream_t stream) {
  const float* X  = (const float*)d_in[0];
  const float* Wq = (const float*)d_in[1];
  const float* bq = (const float*)d_in[2];
  const float* Wk = (const float*)d_in[3];
  const float* bk = (const float*)d_in[4];
  const float* Wv = (const float*)d_in[5];
  const float* bv = (const float*)d_in[6];
  const float* Wo = (const float*)d_in[7];
  const float* bo = (const float*)d_in[8];
  float* out = (float*)d_out;

  char* w = (char*)d_ws;
  u16* Xb  = (u16*)w; w += (size_t)8192 * 1024 * 2;
  u16* Wqb = (u16*)w; w += (size_t)2048 * 1024 * 2;
  u16* Wkb = (u16*)w; w += (size_t)2048 * 1024 * 2;
  u16* Wvb = (u16*)w; w += (size_t)2048 * 1024 * 2;
  u16* Wob = (u16*)w; w += (size_t)1024 * 2048 * 2;
  u16* Qb  = (u16*)w; w += (size_t)8192 * 2048 * 2;
  u16* Kb  = (u16*)w; w += (size_t)8192 * 2048 * 2;
  u16* Vt  = (u16*)w; w += (size_t)8192 * 2048 * 2;   // fp16 [4][2048 d][2048 t]
  u16* AO  = (u16*)w; w += (size_t)8192 * 2048 * 2;
  u16* Scb = (u16*)w; w += (size_t)8192 * 2048 * 2;   // fp16 scores
  u16* Pb  = (u16*)w; w += (size_t)8192 * 2048 * 2;   // fp16 P
  if ((size_t)(w - (char*)d_ws) > ws_size) return;

  // all 5 converts in one launch (blocks: 8192 X + 4 x 2048 weights)
  cvt_all<<<16384, 256, 0, stream>>>(X, Wq, Wk, Wv, Wo, Xb, Wqb, Wkb, Wvb, Wob);

  // projections: M=8192, N=2048, K=1024 (bf16 in; Q/K out bf16, V out fp16-transposed)
  gemmK<1, true, 2, 0><<<dim3(8, 32, 1), 512, 0, stream>>>(Xb, Wqb, Qb, bq,
      1024, 1024, 1024, 2048, 0, 0, 0, 1.0f);
  gemmK<1, true, 2, 0><<<dim3(8, 32, 1), 512, 0, stream>>>(Xb, Wkb, Kb, bk,
      1024, 1024, 1024, 2048, 0, 0, 0, 1.0f);
  gemmK<2, true, 2, 0><<<dim3(8, 32, 1), 512, 0, stream>>>(Xb, Wvb, Vt, bv,
      1024, 1024, 1024, 0, 0, 0, 0, 1.0f);

  // scores: per-batch 2048x2048, K=2048, alpha = 1/sqrt(1024) -> fp16 Sc
  gemmK<3, false, 2, 0><<<dim3(8, 8, 4), 512, 0, stream>>>(Qb, Kb, Scb, nullptr,
      2048, 2048, 2048, 2048, 4194304, 4194304, 4194304, 0.03125f);

  softmax_f16<<<8192, 256, 0, stream>>>(Scb, Pb);

  // O = P @ Vt^T : fp16 x fp16 MFMA, bf16 AO out
  gemmK<1, false, 2, 1><<<dim3(8, 8, 4), 512, 0, stream>>>(Pb, Vt, AO, nullptr,
      2048, 2048, 2048, 2048, 4194304, 4194304, 4194304, 1.0f);

  // out = AO @ Wo^T + bo : M=8192, N=1024, K=2048, fp32 out (256x128 tiles)
  gemmK<0, true, 1, 0><<<dim3(8, 32, 1), 512, 0, stream>>>(AO, Wob, out, bo,
      2048, 2048, 2048, 1024, 0, 0, 0, 1.0f);
}